// Round 3
// baseline (73.051 us; speedup 1.0000x reference)
//
#include <hip/hip_runtime.h>
#include <stdint.h>

#define B_ROWS 128
#define V_COLS 128000
#define BPR 16                       // blocks per row
#define SLICE (V_COLS / BPR)         // 8000 floats
#define N4 (SLICE / 4)               // 2000 float4
#define K1_THREADS 256
#define CAP 2048

// monotone transform on raw float bits: larger float <-> larger uint
__device__ __forceinline__ uint32_t f2u_bits(uint32_t x) {
    return (x & 0x80000000u) ? ~x : (x | 0x80000000u);
}
__device__ __forceinline__ float u2f(uint32_t u) {
    uint32_t x = (u & 0x80000000u) ? (u & 0x7FFFFFFFu) : ~u;
    return __uint_as_float(x);
}

// ---- LDS bitonic (fallback path only), descending, ties: larger idx first ----
__device__ __forceinline__ void bitonic_sort_desc(uint32_t* su, uint32_t* si, int NP) {
    const int tid = threadIdx.x;
    const int nth = blockDim.x;
    for (int ksz = 2; ksz <= NP; ksz <<= 1) {
        for (int j = ksz >> 1; j > 0; j >>= 1) {
            __syncthreads();
            for (int i = tid; i < NP; i += nth) {
                int ixj = i ^ j;
                if (ixj > i) {
                    uint32_t ua = su[i], ub = su[ixj];
                    uint32_t ia = si[i], ib = si[ixj];
                    bool a_lt = (ua < ub) || (ua == ub && ia < ib);
                    if (((i & ksz) == 0) ? a_lt : !a_lt) {
                        su[i] = ub; su[ixj] = ua;
                        si[i] = ib; si[ixj] = ia;
                    }
                }
            }
        }
    }
    __syncthreads();
}

// ---- in-register wave bitonic sort of 64 (u,idx) pairs, descending ----
// after: lane 0 holds largest. ties: larger idx first (matches stable-sort semantics)
__device__ __forceinline__ void wave_sort64_pair_desc(uint32_t& u, uint32_t& i, int lane) {
    #pragma unroll
    for (int ksz = 2; ksz <= 64; ksz <<= 1) {
        #pragma unroll
        for (int j = ksz >> 1; j > 0; j >>= 1) {
            uint32_t ou = (uint32_t)__shfl_xor((int)u, j, 64);
            uint32_t oi = (uint32_t)__shfl_xor((int)i, j, 64);
            bool asc   = (lane & ksz) == 0;
            bool lower = (lane & j) == 0;
            // "self ranks earlier in descending order" == self greater
            bool self_gt = (u > ou) || (u == ou && i > oi);
            bool keep_self = (asc == lower) ? self_gt : !self_gt;
            if (!keep_self) { u = ou; i = oi; }
        }
    }
}

// K1: per (row, 1/16-slice) block: exact top-64 (sorted desc) of the slice.
__global__ __launch_bounds__(K1_THREADS) void topk_slice_kernel(
    const float* __restrict__ logits,
    uint32_t* __restrict__ out_u, uint32_t* __restrict__ out_idx)
{
    __shared__ uint32_t s_u[CAP];
    __shared__ uint32_t s_i[CAP];
    __shared__ uint32_t s_T[4];
    __shared__ uint32_t t_u[64];
    __shared__ uint32_t t_i[64];
    __shared__ int s_cnt;

    const int blk = blockIdx.x;
    const int row = blk >> 4;
    const int q   = blk & 15;
    const int tid = threadIdx.x;
    const int lane = tid & 63;
    const int wv   = tid >> 6;

    if (tid == 0) s_cnt = 0;

    const uint4* src = (const uint4*)(logits + (size_t)row * V_COLS + (size_t)q * SLICE);

    // ---- branch-free batched loads: 8 independent dwordx4 in flight ----
    uint4 g[8];
    #pragma unroll
    for (int j = 0; j < 8; ++j) {
        int i4 = j * K1_THREADS + tid;
        i4 = (i4 < N4) ? i4 : (N4 - 1);      // clamp instead of branch
        g[j] = src[i4];
    }
    // ---- convert in place to monotone uints ----
    #pragma unroll
    for (int j = 0; j < 8; ++j) {
        g[j].x = f2u_bits(g[j].x); g[j].y = f2u_bits(g[j].y);
        g[j].z = f2u_bits(g[j].z); g[j].w = f2u_bits(g[j].w);
    }
    // only j==7 can clamp (7*256+tid >= 2000 for tid >= 208): zero the duplicates
    if (7 * K1_THREADS + tid >= N4) { g[7].x = 0u; g[7].y = 0u; g[7].z = 0u; g[7].w = 0u; }

    // ---- per-thread max ----
    uint32_t mx = 0u;
    #pragma unroll
    for (int j = 0; j < 8; ++j) {
        uint32_t a = g[j].x > g[j].y ? g[j].x : g[j].y;
        uint32_t b = g[j].z > g[j].w ? g[j].z : g[j].w;
        a = a > b ? a : b;
        mx = mx > a ? mx : a;
    }

    // ---- per-wave ascending register sort of the 64 thread-maxes ----
    uint32_t v = mx;
    #pragma unroll
    for (int ksz = 2; ksz <= 64; ksz <<= 1) {
        #pragma unroll
        for (int j = ksz >> 1; j > 0; j >>= 1) {
            uint32_t o = (uint32_t)__shfl_xor((int)v, j, 64);
            bool asc   = (lane & ksz) == 0;
            bool lower = (lane & j) == 0;
            uint32_t mn = (v < o) ? v : o;
            uint32_t mh = (v < o) ? o : v;
            v = (asc == lower) ? mn : mh;
        }
    }
    // lane 48 = 16th-largest thread-max of this wave
    uint32_t Tw = (uint32_t)__shfl((int)v, 48, 64);
    if (lane == 0) s_T[wv] = Tw;
    __syncthreads();
    uint32_t T0 = s_T[0] < s_T[1] ? s_T[0] : s_T[1];
    uint32_t T1 = s_T[2] < s_T[3] ? s_T[2] : s_T[3];
    uint32_t T = T0 < T1 ? T0 : T1;   // >= 64 slice elements are >= T (16 per wave)

    // ---- append candidates (expected ~90 per block) ----
    #pragma unroll
    for (int j = 0; j < 8; ++j) {
        const int base = (j * K1_THREADS + tid) * 4;
        uint32_t uu0 = g[j].x, uu1 = g[j].y, uu2 = g[j].z, uu3 = g[j].w;
        if (uu0 >= T && uu0 != 0u) { int p = atomicAdd(&s_cnt, 1); if (p < CAP) { s_u[p] = uu0; s_i[p] = (uint32_t)(q * SLICE + base + 0); } }
        if (uu1 >= T && uu1 != 0u) { int p = atomicAdd(&s_cnt, 1); if (p < CAP) { s_u[p] = uu1; s_i[p] = (uint32_t)(q * SLICE + base + 1); } }
        if (uu2 >= T && uu2 != 0u) { int p = atomicAdd(&s_cnt, 1); if (p < CAP) { s_u[p] = uu2; s_i[p] = (uint32_t)(q * SLICE + base + 2); } }
        if (uu3 >= T && uu3 != 0u) { int p = atomicAdd(&s_cnt, 1); if (p < CAP) { s_u[p] = uu3; s_i[p] = (uint32_t)(q * SLICE + base + 3); } }
    }
    __syncthreads();
    int cnt = s_cnt; if (cnt > CAP) cnt = CAP;

    if (cnt <= 256) {
        // fast path: pad to 256, per-wave register sort, wave-0 rank-merge
        for (int i = cnt + tid; i < 256; i += K1_THREADS) { s_u[i] = 0u; s_i[i] = 0xFFFFFFFFu; }
        __syncthreads();
        uint32_t cu = s_u[wv * 64 + lane];
        uint32_t ci = s_i[wv * 64 + lane];
        wave_sort64_pair_desc(cu, ci, lane);
        s_u[wv * 64 + lane] = cu;
        s_i[wv * 64 + lane] = ci;
        __syncthreads();
        if (wv == 0) {
            #pragma unroll
            for (int jj = 0; jj < 4; ++jj) {
                uint32_t uc = s_u[jj * 64 + lane];
                uint32_t ic = s_i[jj * 64 + lane];
                int rank = lane;                     // outrankers within own sorted run
                #pragma unroll
                for (int s = 0; s < 4; ++s) {
                    if (s == jj) continue;
                    int pos = 0;
                    #pragma unroll
                    for (int b = 64; b >= 1; b >>= 1) {
                        if (pos + b <= 64) {
                            uint32_t us = s_u[s * 64 + pos + b - 1];
                            uint32_t is = s_i[s * 64 + pos + b - 1];
                            bool outranks = (us > uc) || (us == uc && is > ic);
                            if (outranks) pos += b;
                        }
                    }
                    rank += pos;
                }
                if (rank < 64) { t_u[rank] = uc; t_i[rank] = ic; }
            }
        }
        __syncthreads();
        if (tid < 64) { out_u[blk * 64 + tid] = t_u[tid]; out_idx[blk * 64 + tid] = t_i[tid]; }
    } else {
        // fallback (not expected with normal data): full LDS bitonic
        int NP = 256; while (NP < cnt) NP <<= 1;
        for (int i = cnt + tid; i < NP; i += K1_THREADS) { s_u[i] = 0u; s_i[i] = 0xFFFFFFFFu; }
        bitonic_sort_desc(s_u, s_i, NP);
        if (tid < 64) { out_u[blk * 64 + tid] = s_u[tid]; out_idx[blk * 64 + tid] = s_i[tid]; }
    }
}

// K2: one block per row: rank-merge 16 sorted runs of 64, then filter + sample.
__global__ __launch_bounds__(256) void sample_kernel(
    const uint32_t* __restrict__ in_u, const uint32_t* __restrict__ in_idx,
    const int* __restrict__ kk, const float* __restrict__ pp,
    const float* __restrict__ noise, int* __restrict__ out)
{
    __shared__ uint32_t s_u[BPR * 64];
    __shared__ uint32_t s_i[BPR * 64];
    __shared__ uint32_t t_u[64];
    __shared__ uint32_t t_i[64];
    const int row = blockIdx.x;
    const int tid = threadIdx.x;

    #pragma unroll
    for (int j = 0; j < (BPR * 64) / 256; ++j) {
        int c = j * 256 + tid;
        s_u[c] = in_u[row * (BPR * 64) + c];
        s_i[c] = in_idx[row * (BPR * 64) + c];
    }
    __syncthreads();

    // exact global rank of each candidate via binary search in the other runs
    #pragma unroll
    for (int j = 0; j < (BPR * 64) / 256; ++j) {
        int c = j * 256 + tid;
        int r = c >> 6;
        uint32_t uc = s_u[c];
        uint32_t ic = s_i[c];
        int rank = c & 63;                        // position within own sorted run
        for (int s = 0; s < BPR; ++s) {
            if (s == r) continue;
            int pos = 0;
            #pragma unroll
            for (int b = 64; b >= 1; b >>= 1) {
                if (pos + b <= 64) {
                    uint32_t us = s_u[s * 64 + pos + b - 1];
                    uint32_t is = s_i[s * 64 + pos + b - 1];
                    bool outranks = (us > uc) || (us == uc && is > ic);
                    if (outranks) pos += b;
                }
            }
            rank += pos;
        }
        if (rank < 64) { t_u[rank] = uc; t_i[rank] = ic; }
    }
    __syncthreads();

    if (tid < 64) {
        const int lane = tid;
        float v = u2f(t_u[lane]);             // lane j holds (j+1)-th largest of row
        uint32_t tok = t_i[lane];
        int k = kk[row];
        if (k > 64) k = 64;                    // safety; setup guarantees k<=63
        float p = pp[row];

        // top-k: threshold = k-th largest; keep v >= thr (ties kept, as reference)
        float thrv = __shfl(v, k - 1, 64);
        bool kept = v >= thrv;
        float m = __shfl(v, 0, 64);            // row max
        float e = kept ? expf(v - m) : 0.0f;

        // softmax denom over kept
        float denom = e;
        #pragma unroll
        for (int off = 1; off < 64; off <<= 1) denom += __shfl_xor(denom, off, 64);
        float prob = e / denom;

        // ascending-inclusive cumsum == suffix sum over descending lanes
        float cums = prob;
        #pragma unroll
        for (int off = 1; off < 64; off <<= 1) {
            float o = __shfl_down(cums, off, 64);
            cums += (lane + off < 64) ? o : 0.0f;
        }
        // top-p: mask cumsum <= 1-p, but always keep the max (lane 0)
        bool masked = (cums <= 1.0f - p) && (lane != 0);
        bool surv = kept && !masked;

        // renormalize over survivors
        float e2 = surv ? e : 0.0f;
        float denom2 = e2;
        #pragma unroll
        for (int off = 1; off < 64; off <<= 1) denom2 += __shfl_xor(denom2, off, 64);

        float score = -1.0f;
        uint32_t bidx = 0xFFFFFFFFu;
        if (surv) {
            float nz = noise[(size_t)row * V_COLS + tok];
            score = (e / denom2) / nz;         // probs / Exp(1) noise
            bidx = tok;
        }
        // argmax, tie -> smaller token index (matches jnp first-occurrence)
        #pragma unroll
        for (int off = 1; off < 64; off <<= 1) {
            float os = __shfl_xor(score, off, 64);
            uint32_t oi = __shfl_xor(bidx, off, 64);
            if (os > score || (os == score && oi < bidx)) { score = os; bidx = oi; }
        }
        if (lane == 0) out[row] = (int)bidx;
    }
}

extern "C" void kernel_launch(void* const* d_in, const int* in_sizes, int n_in,
                              void* d_out, int out_size, void* d_ws, size_t ws_size,
                              hipStream_t stream) {
    const float* logits = (const float*)d_in[0];
    const int* kk       = (const int*)d_in[1];
    const float* pp     = (const float*)d_in[2];
    const float* noise  = (const float*)d_in[3];
    int* out            = (int*)d_out;

    uint32_t* ws_u   = (uint32_t*)d_ws;                            // 2048*64 u32
    uint32_t* ws_idx = ws_u + (size_t)B_ROWS * BPR * 64;           // 2048*64 u32

    topk_slice_kernel<<<B_ROWS * BPR, K1_THREADS, 0, stream>>>(logits, ws_u, ws_idx);
    sample_kernel<<<B_ROWS, 256, 0, stream>>>(ws_u, ws_idx, kk, pp, noise, out);
}

// Round 4
// 28.041 us; speedup vs baseline: 2.6052x; 2.6052x over previous
//
#include <hip/hip_runtime.h>
#include <stdint.h>

#define B_ROWS 128
#define V_COLS 128000
#define BPR 16                       // blocks per row
#define SLICE (V_COLS / BPR)         // 8000 floats
#define N4 (SLICE / 4)               // 2000 float4
#define K1_THREADS 256
#define CAP 2048

// monotone transform on raw float bits: larger float <-> larger uint
__device__ __forceinline__ uint32_t f2u_bits(uint32_t x) {
    return (x & 0x80000000u) ? ~x : (x | 0x80000000u);
}
__device__ __forceinline__ float u2f(uint32_t u) {
    uint32_t x = (u & 0x80000000u) ? (u & 0x7FFFFFFFu) : ~u;
    return __uint_as_float(x);
}

__device__ __forceinline__ bool pair_gt(uint32_t au, uint32_t ai, uint32_t bu, uint32_t bi) {
    return (au > bu) || (au == bu && ai > bi);   // desc order, ties: larger idx first
}

// ---- LDS bitonic (fallback path only), descending, ties: larger idx first ----
__device__ __forceinline__ void bitonic_sort_desc(uint32_t* su, uint32_t* si, int NP) {
    const int tid = threadIdx.x;
    const int nth = blockDim.x;
    for (int ksz = 2; ksz <= NP; ksz <<= 1) {
        for (int j = ksz >> 1; j > 0; j >>= 1) {
            __syncthreads();
            for (int i = tid; i < NP; i += nth) {
                int ixj = i ^ j;
                if (ixj > i) {
                    uint32_t ua = su[i], ub = su[ixj];
                    uint32_t ia = si[i], ib = si[ixj];
                    bool a_lt = (ua < ub) || (ua == ub && ia < ib);
                    if (((i & ksz) == 0) ? a_lt : !a_lt) {
                        su[i] = ub; su[ixj] = ua;
                        si[i] = ib; si[ixj] = ia;
                    }
                }
            }
        }
    }
    __syncthreads();
}

// ---- in-register wave bitonic sort of 64 (u,idx) pairs, descending ----
__device__ __forceinline__ void wave_sort64_pair_desc(uint32_t& u, uint32_t& i, int lane) {
    #pragma unroll
    for (int ksz = 2; ksz <= 64; ksz <<= 1) {
        #pragma unroll
        for (int j = ksz >> 1; j > 0; j >>= 1) {
            uint32_t ou = (uint32_t)__shfl_xor((int)u, j, 64);
            uint32_t oi = (uint32_t)__shfl_xor((int)i, j, 64);
            bool asc   = (lane & ksz) == 0;
            bool lower = (lane & j) == 0;
            bool self_gt = pair_gt(u, i, ou, oi);
            bool keep_self = (asc == lower) ? self_gt : !self_gt;
            if (!keep_self) { u = ou; i = oi; }
        }
    }
}

// ---- merge two descending sorted 64-runs (1 elem/lane): keep top-64, sorted desc ----
// stage 0: max(A[lane], B[lane^63]) selects the top-64 multiset (bitonic); then 6-stage cleanup.
__device__ __forceinline__ void merge64_desc(uint32_t& au, uint32_t& ai,
                                             uint32_t bu, uint32_t bi, int lane) {
    uint32_t ou = (uint32_t)__shfl_xor((int)bu, 63, 64);
    uint32_t oi = (uint32_t)__shfl_xor((int)bi, 63, 64);
    if (!pair_gt(au, ai, ou, oi)) { au = ou; ai = oi; }
    #pragma unroll
    for (int j = 32; j >= 1; j >>= 1) {
        uint32_t cu = (uint32_t)__shfl_xor((int)au, j, 64);
        uint32_t ci = (uint32_t)__shfl_xor((int)ai, j, 64);
        bool self_gt = pair_gt(au, ai, cu, ci);
        bool keep_self = ((lane & j) == 0) ? self_gt : !self_gt;
        if (!keep_self) { au = cu; ai = ci; }
    }
}

// K1: per (row, 1/16-slice) block: exact top-64 (sorted desc) of the slice.
__global__ __launch_bounds__(K1_THREADS) void topk_slice_kernel(
    const float* __restrict__ logits,
    uint32_t* __restrict__ out_u, uint32_t* __restrict__ out_idx)
{
    __shared__ uint32_t s_u[CAP];
    __shared__ uint32_t s_i[CAP];
    __shared__ uint32_t s_T[4];
    __shared__ int s_cnt;

    const int blk = blockIdx.x;
    const int row = blk >> 4;
    const int q   = blk & 15;
    const int tid = threadIdx.x;
    const int lane = tid & 63;
    const int wv   = tid >> 6;

    if (tid == 0) s_cnt = 0;

    const uint4* src = (const uint4*)(logits + (size_t)row * V_COLS + (size_t)q * SLICE);

    // ---- branch-free batched loads: 8 independent dwordx4 in flight ----
    uint4 g[8];
    #pragma unroll
    for (int j = 0; j < 8; ++j) {
        int i4 = j * K1_THREADS + tid;
        i4 = (i4 < N4) ? i4 : (N4 - 1);      // clamp instead of branch (only j==7 clamps)
        g[j] = src[i4];
    }
    #pragma unroll
    for (int j = 0; j < 8; ++j) {
        g[j].x = f2u_bits(g[j].x); g[j].y = f2u_bits(g[j].y);
        g[j].z = f2u_bits(g[j].z); g[j].w = f2u_bits(g[j].w);
    }
    if (7 * K1_THREADS + tid >= N4) { g[7].x = 0u; g[7].y = 0u; g[7].z = 0u; g[7].w = 0u; }

    // ---- per-thread max ----
    uint32_t mx = 0u;
    #pragma unroll
    for (int j = 0; j < 8; ++j) {
        uint32_t a = g[j].x > g[j].y ? g[j].x : g[j].y;
        uint32_t b = g[j].z > g[j].w ? g[j].z : g[j].w;
        a = a > b ? a : b;
        mx = mx > a ? mx : a;
    }

    // ---- per-wave ascending register sort of the 64 thread-maxes ----
    uint32_t v = mx;
    #pragma unroll
    for (int ksz = 2; ksz <= 64; ksz <<= 1) {
        #pragma unroll
        for (int j = ksz >> 1; j > 0; j >>= 1) {
            uint32_t o = (uint32_t)__shfl_xor((int)v, j, 64);
            bool asc   = (lane & ksz) == 0;
            bool lower = (lane & j) == 0;
            uint32_t mn = (v < o) ? v : o;
            uint32_t mh = (v < o) ? o : v;
            v = (asc == lower) ? mn : mh;
        }
    }
    // lane 48 = 16th-largest thread-max of this wave -> >=16 elems >= Tw per wave
    uint32_t Tw = (uint32_t)__shfl((int)v, 48, 64);
    if (lane == 0) s_T[wv] = Tw;
    __syncthreads();
    uint32_t T0 = s_T[0] < s_T[1] ? s_T[0] : s_T[1];
    uint32_t T1 = s_T[2] < s_T[3] ? s_T[2] : s_T[3];
    uint32_t T = T0 < T1 ? T0 : T1;   // >= 64 slice elements are >= T

    // ---- append candidates (expected ~90 per block) ----
    #pragma unroll
    for (int j = 0; j < 8; ++j) {
        const int base = (j * K1_THREADS + tid) * 4;
        uint32_t uu0 = g[j].x, uu1 = g[j].y, uu2 = g[j].z, uu3 = g[j].w;
        if (uu0 >= T && uu0 != 0u) { int p = atomicAdd(&s_cnt, 1); if (p < CAP) { s_u[p] = uu0; s_i[p] = (uint32_t)(q * SLICE + base + 0); } }
        if (uu1 >= T && uu1 != 0u) { int p = atomicAdd(&s_cnt, 1); if (p < CAP) { s_u[p] = uu1; s_i[p] = (uint32_t)(q * SLICE + base + 1); } }
        if (uu2 >= T && uu2 != 0u) { int p = atomicAdd(&s_cnt, 1); if (p < CAP) { s_u[p] = uu2; s_i[p] = (uint32_t)(q * SLICE + base + 2); } }
        if (uu3 >= T && uu3 != 0u) { int p = atomicAdd(&s_cnt, 1); if (p < CAP) { s_u[p] = uu3; s_i[p] = (uint32_t)(q * SLICE + base + 3); } }
    }
    __syncthreads();
    int cnt = s_cnt; if (cnt > CAP) cnt = CAP;

    if (cnt <= 256) {
        // fast path: pad to 256, per-wave register sort, wave-0 register tournament merge
        for (int i = cnt + tid; i < 256; i += K1_THREADS) { s_u[i] = 0u; s_i[i] = 0xFFFFFFFFu; }
        __syncthreads();
        uint32_t cu = s_u[wv * 64 + lane];
        uint32_t ci = s_i[wv * 64 + lane];
        wave_sort64_pair_desc(cu, ci, lane);
        s_u[wv * 64 + lane] = cu;
        s_i[wv * 64 + lane] = ci;
        __syncthreads();
        if (wv == 0) {
            uint32_t b1u = s_u[64 + lane],  b1i = s_i[64 + lane];
            uint32_t b2u = s_u[128 + lane], b2i = s_i[128 + lane];
            uint32_t b3u = s_u[192 + lane], b3i = s_i[192 + lane];
            merge64_desc(cu, ci, b1u, b1i, lane);
            merge64_desc(b2u, b2i, b3u, b3i, lane);
            merge64_desc(cu, ci, b2u, b2i, lane);
            out_u[blk * 64 + lane]   = cu;
            out_idx[blk * 64 + lane] = ci;
        }
    } else {
        // fallback (pathological data only): full LDS bitonic
        int NP = 256; while (NP < cnt) NP <<= 1;
        for (int i = cnt + tid; i < NP; i += K1_THREADS) { s_u[i] = 0u; s_i[i] = 0xFFFFFFFFu; }
        bitonic_sort_desc(s_u, s_i, NP);
        if (tid < 64) { out_u[blk * 64 + tid] = s_u[tid]; out_idx[blk * 64 + tid] = s_i[tid]; }
    }
}

// K2: one block per row: register tournament-merge 16 sorted runs, then filter + sample.
__global__ __launch_bounds__(256) void sample_kernel(
    const uint32_t* __restrict__ in_u, const uint32_t* __restrict__ in_idx,
    const int* __restrict__ kk, const float* __restrict__ pp,
    const float* __restrict__ noise, int* __restrict__ out)
{
    __shared__ uint32_t m_u[4 * 64];
    __shared__ uint32_t m_i[4 * 64];
    const int row = blockIdx.x;
    const int tid = threadIdx.x;
    const int lane = tid & 63;
    const int wv   = tid >> 6;

    const uint32_t* bu = in_u  + (size_t)row * (BPR * 64);
    const uint32_t* bi = in_idx + (size_t)row * (BPR * 64);

    // wave w merges its 4 sorted runs entirely in registers
    uint32_t a0u = bu[(wv * 4 + 0) * 64 + lane], a0i = bi[(wv * 4 + 0) * 64 + lane];
    uint32_t a1u = bu[(wv * 4 + 1) * 64 + lane], a1i = bi[(wv * 4 + 1) * 64 + lane];
    uint32_t a2u = bu[(wv * 4 + 2) * 64 + lane], a2i = bi[(wv * 4 + 2) * 64 + lane];
    uint32_t a3u = bu[(wv * 4 + 3) * 64 + lane], a3i = bi[(wv * 4 + 3) * 64 + lane];
    merge64_desc(a0u, a0i, a1u, a1i, lane);
    merge64_desc(a2u, a2i, a3u, a3i, lane);
    merge64_desc(a0u, a0i, a2u, a2i, lane);
    m_u[wv * 64 + lane] = a0u;
    m_i[wv * 64 + lane] = a0i;
    __syncthreads();

    if (wv == 0) {
        uint32_t b1u = m_u[64 + lane],  b1i = m_i[64 + lane];
        uint32_t b2u = m_u[128 + lane], b2i = m_i[128 + lane];
        uint32_t b3u = m_u[192 + lane], b3i = m_i[192 + lane];
        merge64_desc(a0u, a0i, b1u, b1i, lane);
        merge64_desc(b2u, b2i, b3u, b3i, lane);
        merge64_desc(a0u, a0i, b2u, b2i, lane);
        // a0u/a0i: lane j holds the (j+1)-th largest of the row, exact order

        float v = u2f(a0u);
        uint32_t tok = a0i;
        int k = kk[row];
        if (k > 64) k = 64;                    // safety; setup guarantees k<=63
        float p = pp[row];

        // top-k: threshold = k-th largest; keep v >= thr (ties kept, as reference)
        float thrv = __shfl(v, k - 1, 64);
        bool kept = v >= thrv;
        float m = __shfl(v, 0, 64);            // row max
        float e = kept ? expf(v - m) : 0.0f;

        // softmax denom over kept
        float denom = e;
        #pragma unroll
        for (int off = 1; off < 64; off <<= 1) denom += __shfl_xor(denom, off, 64);
        float prob = e / denom;

        // ascending-inclusive cumsum == suffix sum over descending lanes
        float cums = prob;
        #pragma unroll
        for (int off = 1; off < 64; off <<= 1) {
            float o = __shfl_down(cums, off, 64);
            cums += (lane + off < 64) ? o : 0.0f;
        }
        // top-p: mask cumsum <= 1-p, but always keep the max (lane 0)
        bool masked = (cums <= 1.0f - p) && (lane != 0);
        bool surv = kept && !masked;

        // renormalize over survivors
        float e2 = surv ? e : 0.0f;
        float denom2 = e2;
        #pragma unroll
        for (int off = 1; off < 64; off <<= 1) denom2 += __shfl_xor(denom2, off, 64);

        float score = -1.0f;
        uint32_t bidx = 0xFFFFFFFFu;
        if (surv) {
            float nz = noise[(size_t)row * V_COLS + tok];
            score = (e / denom2) / nz;         // probs / Exp(1) noise
            bidx = tok;
        }
        // argmax, tie -> smaller token index (matches jnp first-occurrence)
        #pragma unroll
        for (int off = 1; off < 64; off <<= 1) {
            float os = __shfl_xor(score, off, 64);
            uint32_t oi = __shfl_xor(bidx, off, 64);
            if (os > score || (os == score && oi < bidx)) { score = os; bidx = oi; }
        }
        if (lane == 0) out[row] = (int)bidx;
    }
}

extern "C" void kernel_launch(void* const* d_in, const int* in_sizes, int n_in,
                              void* d_out, int out_size, void* d_ws, size_t ws_size,
                              hipStream_t stream) {
    const float* logits = (const float*)d_in[0];
    const int* kk       = (const int*)d_in[1];
    const float* pp     = (const float*)d_in[2];
    const float* noise  = (const float*)d_in[3];
    int* out            = (int*)d_out;

    uint32_t* ws_u   = (uint32_t*)d_ws;                            // 2048*64 u32
    uint32_t* ws_idx = ws_u + (size_t)B_ROWS * BPR * 64;           // 2048*64 u32

    topk_slice_kernel<<<B_ROWS * BPR, K1_THREADS, 0, stream>>>(logits, ws_u, ws_idx);
    sample_kernel<<<B_ROWS, 256, 0, stream>>>(ws_u, ws_idx, kk, pp, noise, out);
}